// Round 2
// baseline (23269.275 us; speedup 1.0000x reference)
//
#include <hip/hip_runtime.h>
#include <hip/hip_bf16.h>
#include <stdint.h>

#define D 128
#define NITER 8
#define NBLK 768   // 3 blocks/CU * 256 CUs; co-residency guaranteed by __launch_bounds__(256,3)

typedef __bf16 bf16_t;
typedef __bf16 bf16x8 __attribute__((ext_vector_type(8)));
typedef float f32x4 __attribute__((ext_vector_type(4)));

__device__ __forceinline__ f32x4 mfma_bf16(bf16x8 a, bf16x8 b, f32x4 c) {
    return __builtin_amdgcn_mfma_f32_16x16x32_bf16(a, b, c, 0, 0, 0);
}
__device__ __forceinline__ float sigmoidf_fast(float x) { return 1.0f / (1.0f + __expf(-x)); }
__device__ __forceinline__ float tanhf_fast(float x) {
    float e = __expf(-2.0f * fabsf(x));
    float t = (1.0f - e) / (1.0f + e);
    return copysignf(t, x);
}

// ---- dtype-aware element access helpers ----
__device__ __forceinline__ const void* slot_ptr(const void* base, size_t off_elems, int isb) {
    return isb ? (const void*)((const bf16_t*)base + off_elems)
               : (const void*)((const float*)base + off_elems);
}
__device__ __forceinline__ bf16x8 load_h8(const void* h, size_t off, int isb) {
    if (isb) return *reinterpret_cast<const bf16x8*>((const bf16_t*)h + off);
    const float* f = (const float*)h + off;
    f32x4 a = *reinterpret_cast<const f32x4*>(f);
    f32x4 b = *reinterpret_cast<const f32x4*>(f + 4);
    bf16x8 r;
    r[0] = (bf16_t)a[0]; r[1] = (bf16_t)a[1]; r[2] = (bf16_t)a[2]; r[3] = (bf16_t)a[3];
    r[4] = (bf16_t)b[0]; r[5] = (bf16_t)b[1]; r[6] = (bf16_t)b[2]; r[7] = (bf16_t)b[3];
    return r;
}
__device__ __forceinline__ float load_h1(const void* h, size_t off, int isb) {
    return isb ? (float)((const bf16_t*)h)[off] : ((const float*)h)[off];
}
__device__ __forceinline__ void store_h1(void* o, size_t off, float v, int isb) {
    if (isb) ((bf16_t*)o)[off] = (bf16_t)v;
    else     ((float*)o)[off] = v;
}

// ---------------- grid-wide barrier (all blocks resident by construction) ----------------
__device__ __forceinline__ void gsync(int* cnt, int* gen) {
    __syncthreads();
    if (threadIdx.x == 0) {
        __threadfence();   // release my phase's stores device-wide (wbL2)
        int g = __hip_atomic_load(gen, __ATOMIC_RELAXED, __HIP_MEMORY_SCOPE_AGENT);
        int a = __hip_atomic_fetch_add(cnt, 1, __ATOMIC_ACQ_REL, __HIP_MEMORY_SCOPE_AGENT);
        if (a == NBLK - 1) {
            __hip_atomic_store(cnt, 0, __ATOMIC_RELAXED, __HIP_MEMORY_SCOPE_AGENT);
            __hip_atomic_store(gen, g + 1, __ATOMIC_RELEASE, __HIP_MEMORY_SCOPE_AGENT);
        } else {
            while (__hip_atomic_load(gen, __ATOMIC_ACQUIRE, __HIP_MEMORY_SCOPE_AGENT) == g)
                __builtin_amdgcn_s_sleep(2);
        }
        __threadfence();   // acquire: invalidate L1/L2 before reading others' data
    }
    __syncthreads();
}

// ---------------- phase bodies ----------------
__device__ __forceinline__ void scan_body(const int* __restrict__ counts,
                                          int* __restrict__ row_ptr,
                                          int* __restrict__ cursor, int n) {
    __shared__ __align__(16) int sums[256];
    __shared__ __align__(16) int pre[257];
    const int tid = threadIdx.x;
    const int chunk = (n + 255) >> 8;
    int start = tid * chunk, end = start + chunk;
    if (start > n) start = n;
    if (end > n) end = n;
    int s = 0;
    for (int i = start; i < end; ++i) s += counts[i];
    sums[tid] = s;
    __syncthreads();
    if (tid == 0) {
        int acc = 0;
        for (int i = 0; i < 256; ++i) { pre[i] = acc; acc += sums[i]; }
        pre[256] = acc;
    }
    __syncthreads();
    int off = pre[tid];
    for (int i = start; i < end; ++i) {
        row_ptr[i] = off;
        cursor[i] = off;
        off += counts[i];
    }
    if (tid == 0) row_ptr[n] = pre[256];
}

__device__ __forceinline__ void mlp_body(
    const void* __restrict__ xbase, size_t x_off, const bf16_t* __restrict__ W0,
    const bf16_t* __restrict__ b0, const bf16_t* __restrict__ W1,
    const bf16_t* __restrict__ b1, bf16_t* __restrict__ out, int N,
    bool swap, int blk, int isb)
{
    __shared__ __align__(16) bf16_t hbuf[4][16][136];
    const void* x = slot_ptr(xbase, x_off, isb);
    const int tid = threadIdx.x;
    const int wave = tid >> 6, lane = tid & 63;
    const int m = lane & 15, q = lane >> 4;
    const int rowbase = blk * 64 + wave * 16;
    int lrow = rowbase + m;
    if (lrow > N - 1) lrow = N - 1;
    const int arow = swap ? (lrow ^ 1) : lrow;

    bf16x8 afrag[4];
    #pragma unroll
    for (int k0 = 0; k0 < 4; ++k0)
        afrag[k0] = load_h8(x, (size_t)arow * D + k0 * 32 + q * 8, isb);

    #pragma unroll
    for (int c = 0; c < 8; ++c) {
        f32x4 acc = {0.f, 0.f, 0.f, 0.f};
        #pragma unroll
        for (int k0 = 0; k0 < 4; ++k0) {
            bf16x8 b = *reinterpret_cast<const bf16x8*>(W0 + (size_t)(c * 16 + m) * D + k0 * 32 + q * 8);
            acc = mfma_bf16(afrag[k0], b, acc);
        }
        const float bias = (float)b0[c * 16 + m];
        #pragma unroll
        for (int r = 0; r < 4; ++r) {
            float v = acc[r] + bias;
            hbuf[wave][q * 4 + r][c * 16 + m] = (bf16_t)(v > 0.f ? v : 0.f);
        }
    }
    __syncthreads();

    bf16x8 hfrag[4];
    #pragma unroll
    for (int k0 = 0; k0 < 4; ++k0)
        hfrag[k0] = *reinterpret_cast<const bf16x8*>(&hbuf[wave][m][k0 * 32 + q * 8]);

    #pragma unroll
    for (int c = 0; c < 8; ++c) {
        f32x4 acc = {0.f, 0.f, 0.f, 0.f};
        #pragma unroll
        for (int k0 = 0; k0 < 4; ++k0) {
            bf16x8 b = *reinterpret_cast<const bf16x8*>(W1 + (size_t)(c * 16 + m) * D + k0 * 32 + q * 8);
            acc = mfma_bf16(hfrag[k0], b, acc);
        }
        const float bias = (float)b1[c * 16 + m];
        #pragma unroll
        for (int r = 0; r < 4; ++r) {
            int orow = rowbase + q * 4 + r;
            if (orow < N) out[(size_t)orow * D + c * 16 + m] = (bf16_t)(acc[r] + bias);
        }
    }
}

// segment sum: one wave handles TWO dst rows (2 independent gather chains for MLP)
__device__ __forceinline__ void seg_rows2(
    const bf16_t* __restrict__ msg, const int* __restrict__ row_ptr,
    const int* __restrict__ srcs, bf16_t* __restrict__ out,
    int Ndst, int Nsrc, int E, int d0)
{
    const int lane = threadIdx.x & 63;
    const int d1 = d0 + 1;
    int s0 = 0, e0 = 0, s1 = 0, e1 = 0;
    if (d0 < Ndst) { s0 = row_ptr[d0]; e0 = row_ptr[d0 + 1]; }
    if (d1 < Ndst) { s1 = row_ptr[d1]; e1 = row_ptr[d1 + 1]; }
    s0 = s0 < 0 ? 0 : (s0 > E ? E : s0); e0 = e0 < s0 ? s0 : (e0 > E ? E : e0);
    s1 = s1 < 0 ? 0 : (s1 > E ? E : s1); e1 = e1 < s1 ? s1 : (e1 > E ? E : e1);
    float p00 = 0.f, p01 = 0.f, p10 = 0.f, p11 = 0.f;
    int i0 = s0, i1 = s1;
    int n0 = (i0 < e0) ? srcs[i0] : 0;
    int n1 = (i1 < e1) ? srcs[i1] : 0;
    while (i0 < e0 || i1 < e1) {
        if (i0 < e0) {
            int src = n0; src = src < 0 ? 0 : (src >= Nsrc ? Nsrc - 1 : src);
            unsigned v = *reinterpret_cast<const unsigned*>(msg + (size_t)src * D + lane * 2);
            if (i0 + 1 < e0) n0 = srcs[i0 + 1];
            union { unsigned u; float f; } lo, hi;
            lo.u = v << 16; hi.u = v & 0xffff0000u;
            p00 += lo.f; p01 += hi.f;
            ++i0;
        }
        if (i1 < e1) {
            int src = n1; src = src < 0 ? 0 : (src >= Nsrc ? Nsrc - 1 : src);
            unsigned v = *reinterpret_cast<const unsigned*>(msg + (size_t)src * D + lane * 2);
            if (i1 + 1 < e1) n1 = srcs[i1 + 1];
            union { unsigned u; float f; } lo, hi;
            lo.u = v << 16; hi.u = v & 0xffff0000u;
            p10 += lo.f; p11 += hi.f;
            ++i1;
        }
    }
    if (d0 < Ndst) {
        union { unsigned u; bf16_t b[2]; } pk;
        pk.b[0] = (bf16_t)p00; pk.b[1] = (bf16_t)p01;
        *reinterpret_cast<unsigned*>(out + (size_t)d0 * D + lane * 2) = pk.u;
    }
    if (d1 < Ndst) {
        union { unsigned u; bf16_t b[2]; } pk;
        pk.b[0] = (bf16_t)p10; pk.b[1] = (bf16_t)p11;
        *reinterpret_cast<unsigned*>(out + (size_t)d1 * D + lane * 2) = pk.u;
    }
}

template<int KX>
__device__ __forceinline__ void gru_body(
    const bf16_t* __restrict__ x0, const bf16_t* __restrict__ x1,
    const void* __restrict__ slotbase, size_t h_off, size_t o_off,
    const bf16_t* __restrict__ Wih, const bf16_t* __restrict__ Whh,
    const bf16_t* __restrict__ bih, const bf16_t* __restrict__ bhh,
    int N, int blk, int isb)
{
    const void* h = slot_ptr(slotbase, h_off, isb);
    void* outp = (void*)slot_ptr(slotbase, o_off, isb);
    const int tid = threadIdx.x;
    const int wave = tid >> 6, lane = tid & 63;
    const int m = lane & 15, q = lane >> 4;
    const int rowbase = blk * 64 + wave * 16;
    int lrow = rowbase + m;
    if (lrow > N - 1) lrow = N - 1;

    constexpr int NKX = KX / 32;
    bf16x8 xfrag[NKX];
    #pragma unroll
    for (int kk = 0; kk < NKX; ++kk) {
        const bf16_t* p = (kk < 4) ? (x0 + (size_t)lrow * D + kk * 32)
                                   : (x1 + (size_t)lrow * D + (kk - 4) * 32);
        xfrag[kk] = *reinterpret_cast<const bf16x8*>(p + q * 8);
    }
    bf16x8 hfrag[4];
    #pragma unroll
    for (int kk = 0; kk < 4; ++kk)
        hfrag[kk] = load_h8(h, (size_t)lrow * D + kk * 32 + q * 8, isb);

    #pragma unroll
    for (int c = 0; c < 8; ++c) {
        f32x4 gi[3], gh[3];
        #pragma unroll
        for (int p = 0; p < 3; ++p) {
            gi[p] = {0.f, 0.f, 0.f, 0.f};
            gh[p] = {0.f, 0.f, 0.f, 0.f};
        }
        #pragma unroll
        for (int p = 0; p < 3; ++p) {
            const bf16_t* wi = Wih + (size_t)(p * 128 + c * 16 + m) * KX + q * 8;
            #pragma unroll
            for (int kk = 0; kk < NKX; ++kk)
                gi[p] = mfma_bf16(xfrag[kk], *reinterpret_cast<const bf16x8*>(wi + kk * 32), gi[p]);
            const bf16_t* wh = Whh + (size_t)(p * 128 + c * 16 + m) * D + q * 8;
            #pragma unroll
            for (int kk = 0; kk < 4; ++kk)
                gh[p] = mfma_bf16(hfrag[kk], *reinterpret_cast<const bf16x8*>(wh + kk * 32), gh[p]);
        }
        const int col = c * 16 + m;
        const float bi0 = (float)bih[col], bi1 = (float)bih[128 + col], bi2 = (float)bih[256 + col];
        const float bh0 = (float)bhh[col], bh1 = (float)bhh[128 + col], bh2 = (float)bhh[256 + col];
        #pragma unroll
        for (int r = 0; r < 4; ++r) {
            int orow = rowbase + q * 4 + r;
            bool valid = orow < N;
            float hold = valid ? load_h1(h, (size_t)orow * D + col, isb) : 0.f;
            float rg = sigmoidf_fast(gi[0][r] + bi0 + gh[0][r] + bh0);
            float zg = sigmoidf_fast(gi[1][r] + bi1 + gh[1][r] + bh1);
            float ng = tanhf_fast(gi[2][r] + bi2 + rg * (gh[2][r] + bh2));
            float hv = (1.f - zg) * ng + zg * hold;
            if (valid) store_h1(outp, (size_t)orow * D + col, hv, isb);
        }
    }
}

// ---------------- mega persistent kernel ----------------
struct MegaArgs {
    const unsigned* dsrc;
    const int* l_edge; const int* c_edge;
    const void* l_in; const void* c_in; void* out;
    const void* wsrc[20]; bf16_t* wdst[20]; int wn[20];
    int* flag; int* cnt; int* gen; int* tk;
    int* ptr_c; int* ptr_l; int* cnt_c; int* cnt_l;
    int* cur_c; int* cur_l; int* src_c; int* src_l;
    bf16_t* msgA; bf16_t* msgB; bf16_t* msgC; bf16_t* aggC; bf16_t* aggL;
    int L; int C; int E;
};

__global__ void init_kernel(int* p) {
    if (threadIdx.x < 18) p[threadIdx.x] = 0;   // cnt, gen, tk[16]
}

__global__ __launch_bounds__(256, 3) void mega_kernel(MegaArgs P) {
    const int tid = threadIdx.x;
    const int bid = blockIdx.x;
    const int gidx = bid * 256 + tid;
    const int gstride = NBLK * 256;

    const int L = P.L, C = P.C, E = P.E;
    const size_t LD = (size_t)L * D, CD = (size_t)C * D;
    const size_t c_base = 9 * LD;
    const int NBL = (L + 63) / 64, NBC = (C + 63) / 64;
    const int JC = (C + 7) / 8, JL = (L + 7) / 8;   // seg jobs (8 rows/block, 2/wave)

    __shared__ int sbase;
    __shared__ int hits;

    // ---- P0: detect dtype (block 0); zero degree counters (all blocks) ----
    if (bid == 0) {
        if (tid == 0) hits = 0;
        __syncthreads();
        unsigned v = P.dsrc[tid];
        unsigned ex = ((v & 0xffffu) >> 7) & 0xff;
        if (ex >= 110 && ex <= 132) atomicAdd(&hits, 1);
        __syncthreads();
        if (tid == 0) *P.flag = (hits > 192) ? 1 : 0;
    }
    for (int i = gidx; i < C; i += gstride) P.cnt_c[i] = 0;
    for (int i = gidx; i < L; i += gstride) P.cnt_l[i] = 0;
    gsync(P.cnt, P.gen);

    const int isb = *P.flag;

    // ---- P1: weight canonicalize + degree count + initial-embedding outcopy ----
    for (int j = 0; j < 20; ++j) {
        const void* s = P.wsrc[j];
        bf16_t* dptr = P.wdst[j];
        const int n = P.wn[j];
        for (int i = gidx; i < n; i += gstride)
            dptr[i] = isb ? ((const bf16_t*)s)[i] : (bf16_t)((const float*)s)[i];
    }
    for (int i = gidx; i < E; i += gstride) {
        atomicAdd(&P.cnt_c[P.c_edge[i]], 1);
        atomicAdd(&P.cnt_l[P.l_edge[i]], 1);
    }
    for (int i = gidx; i < (int)LD; i += gstride) {
        if (isb) ((uint16_t*)P.out)[i] = ((const uint16_t*)P.l_in)[i];
        else     ((float*)P.out)[i]    = ((const float*)P.l_in)[i];
    }
    for (int i = gidx; i < (int)CD; i += gstride) {
        if (isb) ((uint16_t*)P.out)[c_base + i] = ((const uint16_t*)P.c_in)[i];
        else     ((float*)P.out)[c_base + i]    = ((const float*)P.c_in)[i];
    }
    gsync(P.cnt, P.gen);

    // ---- P2: exclusive scans (2 blocks) ----
    if (bid == 0)      scan_body(P.cnt_c, P.ptr_c, P.cur_c, C);
    else if (bid == 1) scan_body(P.cnt_l, P.ptr_l, P.cur_l, L);
    gsync(P.cnt, P.gen);

    // ---- P3: CSR fill ----
    for (int i = gidx; i < E; i += gstride) {
        int p = atomicAdd(&P.cur_c[P.c_edge[i]], 1);
        P.src_c[p] = P.l_edge[i];
        int q = atomicAdd(&P.cur_l[P.l_edge[i]], 1);
        P.src_l[q] = P.c_edge[i];
    }
    gsync(P.cnt, P.gen);

    // ---- iteration loop: mlp | seg | gru, grid-synced ----
    for (int t = 1; t <= NITER; ++t) {
        const size_t hl = (size_t)(t - 1) * LD, hl_new = (size_t)t * LD;
        const size_t hc = c_base + (size_t)(t - 1) * CD, hc_new = c_base + (size_t)t * CD;

        // -- mlp phase: ticketed jobs (batch 4) --
        {
            int* tkp = &P.tk[2 * (t - 1)];
            const int njobs = 2 * NBL + NBC;
            for (;;) {
                __syncthreads();
                if (tid == 0)
                    sbase = __hip_atomic_fetch_add(tkp, 1, __ATOMIC_RELAXED, __HIP_MEMORY_SCOPE_AGENT) * 4;
                __syncthreads();
                const int base = sbase;
                if (base >= njobs) break;
                const int jend = (base + 4 < njobs) ? base + 4 : njobs;
                for (int b = base; b < jend; ++b) {
                    if (b < NBL)
                        mlp_body(P.out, hl, P.wdst[8], P.wdst[9], P.wdst[10], P.wdst[11], P.msgC, L, true, b, isb);
                    else if (b < 2 * NBL)
                        mlp_body(P.out, hl, P.wdst[0], P.wdst[1], P.wdst[2], P.wdst[3], P.msgA, L, false, b - NBL, isb);
                    else
                        mlp_body(P.out, hc, P.wdst[4], P.wdst[5], P.wdst[6], P.wdst[7], P.msgB, C, false, b - 2 * NBL, isb);
                }
            }
        }
        gsync(P.cnt, P.gen);

        // -- seg phase: static stride, 8 rows/block (2 rows/wave) --
        {
            const int wave = tid >> 6;
            for (int b = bid; b < JC + JL; b += NBLK) {
                if (b < JC)
                    seg_rows2(P.msgA, P.ptr_c, P.src_c, P.aggC, C, L, E, b * 8 + wave * 2);
                else
                    seg_rows2(P.msgB, P.ptr_l, P.src_l, P.aggL, L, C, E, (b - JC) * 8 + wave * 2);
            }
        }
        gsync(P.cnt, P.gen);

        // -- gru phase: ticketed jobs (batch 2) --
        {
            int* tkp = &P.tk[2 * (t - 1) + 1];
            const int njobs = NBL + NBC;
            for (;;) {
                __syncthreads();
                if (tid == 0)
                    sbase = __hip_atomic_fetch_add(tkp, 1, __ATOMIC_RELAXED, __HIP_MEMORY_SCOPE_AGENT) * 2;
                __syncthreads();
                const int base = sbase;
                if (base >= njobs) break;
                const int jend = (base + 2 < njobs) ? base + 2 : njobs;
                for (int b = base; b < jend; ++b) {
                    if (b < NBL)
                        gru_body<256>(P.aggL, P.msgC, P.out, hl, hl_new,
                                      P.wdst[16], P.wdst[17], P.wdst[18], P.wdst[19], L, b, isb);
                    else
                        gru_body<128>(P.aggC, P.aggC, P.out, hc, hc_new,
                                      P.wdst[12], P.wdst[13], P.wdst[14], P.wdst[15], C, b - NBL, isb);
                }
            }
        }
        gsync(P.cnt, P.gen);
    }
}

extern "C" void kernel_launch(void* const* d_in, const int* in_sizes, int n_in,
                              void* d_out, int out_size, void* d_ws, size_t ws_size,
                              hipStream_t stream) {
    const int E = in_sizes[2];
    const int L = in_sizes[4] / D;
    const int C = in_sizes[5] / D;

    // ---- workspace carve ----
    char* w = (char*)d_ws;
    auto alloc = [&](size_t bytes) {
        void* p = (void*)w;
        w += (bytes + 255) & ~(size_t)255;
        return p;
    };
    int* barmem = (int*)alloc(64 * 4);        // [0]=cnt, [1]=gen, [2..17]=tickets
    int* flag   = (int*)alloc(4);
    int* ptr_c  = (int*)alloc((size_t)(C + 1) * 4);
    int* ptr_l  = (int*)alloc((size_t)(L + 1) * 4);
    int* cnt_c  = (int*)alloc((size_t)C * 4);
    int* cnt_l  = (int*)alloc((size_t)L * 4);
    int* cur_c  = (int*)alloc((size_t)C * 4);
    int* cur_l  = (int*)alloc((size_t)L * 4);
    int* src_c  = (int*)alloc((size_t)E * 4);
    int* src_l  = (int*)alloc((size_t)E * 4);

    MegaArgs P;
    for (int i = 6; i < 26; ++i) {
        P.wsrc[i - 6] = d_in[i];
        P.wn[i - 6] = in_sizes[i];
        P.wdst[i - 6] = (bf16_t*)alloc((size_t)in_sizes[i] * 2);
    }
    P.msgA = (bf16_t*)alloc((size_t)L * D * 2);
    P.msgB = (bf16_t*)alloc((size_t)C * D * 2);
    P.msgC = (bf16_t*)alloc((size_t)L * D * 2);
    P.aggC = (bf16_t*)alloc((size_t)C * D * 2);
    P.aggL = (bf16_t*)alloc((size_t)L * D * 2);

    P.dsrc = (const unsigned*)d_in[4];
    P.l_edge = (const int*)d_in[2];
    P.c_edge = (const int*)d_in[3];
    P.l_in = d_in[4];
    P.c_in = d_in[5];
    P.out = d_out;
    P.flag = flag;
    P.cnt = &barmem[0];
    P.gen = &barmem[1];
    P.tk = &barmem[2];
    P.ptr_c = ptr_c; P.ptr_l = ptr_l;
    P.cnt_c = cnt_c; P.cnt_l = cnt_l;
    P.cur_c = cur_c; P.cur_l = cur_l;
    P.src_c = src_c; P.src_l = src_l;
    P.L = L; P.C = C; P.E = E;

    init_kernel<<<1, 64, 0, stream>>>(barmem);
    mega_kernel<<<NBLK, 256, 0, stream>>>(P);
}